// Round 9
// baseline (17062.592 us; speedup 1.0000x reference)
//
#include <hip/hip_runtime.h>
#include <hip/hip_bf16.h>
#include <math.h>

// PRNN round 9: inv-free persistent kernel with per-XCD L2-resident h replica.
// 256 WGs x 1024 threads (1/CU). WG (ch,cg): 128 rows x 16 cols, full composite
// K=2560. Exchange (h,x) via sc0sc1 pub buffers (never in L2); each XCD's WGs
// cooperatively stage the full h|x into an XCD-private replica (normal stores ->
// local L2 dirty); consumers read replica with sc0 loads (L1-bypass, L2 hits).
// NO acquire-inv, NO wbl2: read-only data (Wdec,x,biases) stays L2-warm forever.
// XCD self-identification via s_getreg(HW_REG_XCC_ID); dynamic rank/count.
// Replica ring depth 2 guarded by staged/doneB/doneD monotone counters.
// y_t = h_t@Wdec^T + b_dec ; h_t = (1-s)h_{t-1} + s*a*tanh(x_t@Wenc^T + b_enc + h_{t-1}@Wrec^T + b_rec)

#define B_   256
#define T_   512
#define NI_  512
#define NH_  2048
#define NO_  256

typedef __bf16 bf16_t;
typedef __bf16 bf16x8 __attribute__((ext_vector_type(8)));
typedef float  f32x4  __attribute__((ext_vector_type(4)));

#define MFMA16(a,b,c) __builtin_amdgcn_mfma_f32_16x16x32_bf16((a),(b),(c),0,0,0)

// HW_REG_XCC_ID: id=20, offset=0, width=32 -> simm16 = 20 | (31<<11)
#define XCC_HWREG_IMM (20 | (31 << 11))

__device__ __forceinline__ void ld_sc0_x4(bf16x8& d, const void* p) {   // issue only
  asm volatile("global_load_dwordx4 %0, %1, off sc0" : "=v"(d) : "v"(p));
}
__device__ __forceinline__ void ld_sc01_u32(unsigned& d, const void* p) { // issue only
  asm volatile("global_load_dword %0, %1, off sc0 sc1" : "=v"(d) : "v"(p));
}
__device__ __forceinline__ void st_sc01_u32(void* p, unsigned v) {
  asm volatile("global_store_dword %0, %1, off sc0 sc1" :: "v"(p), "v"(v));
}
#define WAIT_VM0() do { asm volatile("s_waitcnt vmcnt(0)" ::: "memory"); \
                        __builtin_amdgcn_sched_barrier(0); } while (0)
#define WAIT_VM(n) do { asm volatile("s_waitcnt vmcnt(" #n ")" ::: "memory"); \
                        __builtin_amdgcn_sched_barrier(0); } while (0)

__device__ __forceinline__ void spin_ge(int* p, int tgt) {
  while (__hip_atomic_load(p, __ATOMIC_RELAXED, __HIP_MEMORY_SCOPE_AGENT) < tgt)
    __builtin_amdgcn_s_sleep(1);
}
__device__ __forceinline__ void bump(int* p) {
  __hip_atomic_fetch_add(p, 1, __ATOMIC_RELAXED, __HIP_MEMORY_SCOPE_AGENT);
}

__device__ __forceinline__ int* s_flg(int* s, int c)        { return s + c*16; }
__device__ __forceinline__ int* s_start(int* s)             { return s + 4096; }
__device__ __forceinline__ int* s_reg(int* s, int x)        { return s + 4160 + x*16; }
__device__ __forceinline__ int* s_stg(int* s, int x, int p) { return s + 4352 + (x*2+p)*16; }
__device__ __forceinline__ int* s_dnb(int* s, int x, int p) { return s + 4608 + (x*2+p)*16; }
__device__ __forceinline__ int* s_dnd(int* s, int x, int p) { return s + 4864 + (x*2+p)*16; }

__global__ __launch_bounds__(256) void k_cvt(const float* __restrict__ src,
                                             bf16_t* __restrict__ dst, int n) {
  int i = blockIdx.x * 256 + threadIdx.x;
  const int stride = gridDim.x * 256;
  for (; i < n; i += stride) dst[i] = (bf16_t)src[i];
}

// Stage S_{t-1}|x_t (pub slot t&1) into this XCD's replica slot t&1, then wait
// until all local WGs have staged. Flag target t+1; ring guards doneB/doneD.
__device__ __forceinline__ void stage_and_wait(
    int t, int tid, int xcd, int rank, int cnt,
    const char* pubH, const char* pubX,
    bf16_t* repH_x, bf16_t* repX_x, int* sync_)
{
  const int p = t & 1, K = t >> 1;
  const char* pubHs = pubH + (size_t)p * (256*4096);
  const char* pubXs = pubX + (size_t)p * (256*1024);
  char* rH = reinterpret_cast<char*>(repH_x) + (size_t)p * ((size_t)256*2048*2);
  char* rX = reinterpret_cast<char*>(repX_x) + (size_t)p * ((size_t)256*512*2);

  if (tid == 256) spin_ge(s_dnb(sync_, xcd, p), cnt * K);
  if (tid == 257) spin_ge(s_dnd(sync_, xcd, p), cnt * K);
  __syncthreads();

  for (int c0 = rank; c0 < 256; c0 += cnt * 8) {
    if (tid < 8) { int c = c0 + tid*cnt; if (c < 256) spin_ge(s_flg(sync_, c), t + 1); }
    __syncthreads();
    unsigned hreg[8], xreg[8];
    #pragma unroll
    for (int i = 0; i < 8; ++i) {
      const int c = c0 + i*cnt;
      if (c < 256) {
        ld_sc01_u32(hreg[i], pubHs + (size_t)c*4096 + tid*4);
        if (tid < 256) ld_sc01_u32(xreg[i], pubXs + (size_t)c*1024 + tid*4);
      }
    }
    WAIT_VM0();
    #pragma unroll
    for (int i = 0; i < 8; ++i) {
      const int c = c0 + i*cnt;
      if (c < 256) {
        const int chc = c >> 7, cgc = c & 127;
        const int r = tid >> 3, q = tid & 7;
        *reinterpret_cast<unsigned*>(
            rH + ((size_t)(chc*128 + r)*2048 + cgc*16 + q*2)*2) = hreg[i];
        if (tid < 256) {
          const int rx = tid >> 1, p2 = tid & 1;
          *reinterpret_cast<unsigned*>(
              rX + ((size_t)(chc*128 + rx)*512 + cgc*4 + p2*2)*2) = xreg[i];
        }
      }
    }
    __syncthreads();   // drains this batch's replica stores (compiler waitcnt)
  }
  if (tid == 0) { bump(s_stg(sync_, xcd, p)); spin_ge(s_stg(sync_, xcd, p), cnt*(K+1)); }
  __syncthreads();
}

// Decoder tile: y[dr..+16][dc..+16] = h @ Wdec^T + b_dec, from the replica.
__device__ __forceinline__ void dec_tile(int bid, int tid,
    const bf16_t* repHs, const bf16_t* Wdec, const float* b_dec,
    float* y_out, float* Scr) {
  const int lane = tid & 63, w = tid >> 6, fl = lane & 15, kg = lane >> 4;
  const int dr = (bid >> 4) * 16, dc = (bid & 15) * 16;
  bf16x8 hf[4];
  const char* hb = reinterpret_cast<const char*>(repHs) + (size_t)(dr + fl) * 4096;
  #pragma unroll
  for (int i = 0; i < 4; ++i)
    ld_sc0_x4(hf[i], hb + (size_t)(w*128 + i*32 + kg*8)*2);
  WAIT_VM0();
  f32x4 dacc = {0.f, 0.f, 0.f, 0.f};
  #pragma unroll
  for (int i = 0; i < 4; ++i) {
    bf16x8 wf = *reinterpret_cast<const bf16x8*>(
        Wdec + (size_t)(dc + fl) * NH_ + w*128 + i*32 + kg*8);
    dacc = MFMA16(hf[i], wf, dacc);
  }
  __syncthreads();
  #pragma unroll
  for (int j = 0; j < 4; ++j)
    Scr[w*256 + (kg*4 + j)*16 + fl] = dacc[j];
  __syncthreads();
  if (tid < 256) {
    const int r = tid >> 4, c = tid & 15;
    float s = b_dec[dc + c];
    #pragma unroll
    for (int ww = 0; ww < 16; ++ww) s += Scr[ww*256 + r*16 + c];
    y_out[(size_t)(dr + r) * NO_ + dc + c] = s;
  }
}

__global__ __launch_bounds__(1024, 1) void k_prnn(
    const float* __restrict__ x,
    const float* __restrict__ dt_p, const float* __restrict__ a_p,
    const float* __restrict__ Wrec, const float* __restrict__ Wenc,
    const bf16_t* __restrict__ Wdec,
    const float* __restrict__ b_rec, const float* __restrict__ b_enc,
    const float* __restrict__ b_dec,
    char* __restrict__ pubH, char* __restrict__ pubX,
    bf16_t* __restrict__ repH, bf16_t* __restrict__ repX,
    int* __restrict__ sync_, float* __restrict__ out)
{
  __shared__ alignas(16) bf16x8 Wl[320 * 16];   // 80KB: [granule][col]
  __shared__ alignas(16) float  Scr[4352];      // 17KB: reduce / dec scratch
  __shared__ alignas(16) bf16_t Ts[2048];       // 4KB:  h-tile transpose
  __shared__ int sh_xcd, sh_rank, sh_cnt;

  const int tid  = threadIdx.x;
  const int lane = tid & 63;
  const int fl   = lane & 15;
  const int kg   = lane >> 4;
  const int w    = tid >> 6;     // wave 0..15
  const int rt   = w & 7;        // row tile
  const int kh   = w >> 3;       // K half
  const int bid  = blockIdx.x;
  const int ch   = bid >> 7;     // row half
  const int cg   = bid & 127;    // col group
  const int rbase = ch * 128;

  // ---- registration: physical XCD id, local rank, local count
  if (tid == 0) {
    const int xcd = (int)(__builtin_amdgcn_s_getreg(XCC_HWREG_IMM) & 7u);
    const int rank = __hip_atomic_fetch_add(s_reg(sync_, xcd), 1,
                       __ATOMIC_RELAXED, __HIP_MEMORY_SCOPE_AGENT);
    bump(s_start(sync_));
    spin_ge(s_start(sync_), 256);
    sh_xcd = xcd; sh_rank = rank;
    sh_cnt = __hip_atomic_load(s_reg(sync_, xcd), __ATOMIC_RELAXED,
                               __HIP_MEMORY_SCOPE_AGENT);
  }
  __syncthreads();
  const int xcd = sh_xcd, rank = sh_rank, cnt = sh_cnt;

  bf16_t* repH_x = repH + (size_t)xcd * 2 * ((size_t)256*2048);
  bf16_t* repX_x = repX + (size_t)xcd * 2 * ((size_t)256*512);

  const float sgate = 1.f / (1.f + expf(-dt_p[0]));
  const float av = a_p[0];
  const float gi = 1.f - sgate;
  const float sav = sgate * av;
  const int col_g = cg * 16 + fl;
  const float bias = b_rec[col_g] + b_enc[col_g];

  f32x4 hr = {0.f, 0.f, 0.f, 0.f};   // master state (kh==0 waves)

  // ---- prologue: W slice -> LDS [granule][col] (conflict-free reads)
  {
    const int wc = tid & 15, part = tid >> 4;
    const int c_g = cg * 16 + wc;
    #pragma unroll
    for (int i = 0; i < 5; ++i) {
      const int g = part * 5 + i;        // 0..319
      const int k = g * 8;
      const float* src = (k < NH_) ? (Wrec + (size_t)c_g * NH_ + k)
                                   : (Wenc + (size_t)c_g * NI_ + (k - NH_));
      float4 f0 = reinterpret_cast<const float4*>(src)[0];
      float4 f1 = reinterpret_cast<const float4*>(src)[1];
      bf16x8 w8 = {(bf16_t)f0.x, (bf16_t)f0.y, (bf16_t)f0.z, (bf16_t)f0.w,
                   (bf16_t)f1.x, (bf16_t)f1.y, (bf16_t)f1.z, (bf16_t)f1.w};
      Wl[g * 16 + wc] = w8;
    }
  }
  // ---- prologue: publish S_{-1}=0 and x_0 (pub slot 0), flag #1
  st_sc01_u32(pubH + (size_t)bid*4096 + tid*4, 0u);
  if (tid < 256) {
    const int r = tid >> 1, pr = tid & 1;
    const float* xs = x + ((size_t)(rbase + r) * T_ + 0) * NI_ + cg*4 + pr*2;
    union { unsigned u; bf16_t h2[2]; } pk;
    pk.h2[0] = (bf16_t)xs[0]; pk.h2[1] = (bf16_t)xs[1];
    st_sc01_u32(pubX + (size_t)bid*1024 + r*8 + pr*4, pk.u);
  }
  WAIT_VM0();
  __syncthreads();
  if (tid == 0) bump(s_flg(sync_, bid));

  #pragma unroll 1
  for (int t = 0; t < T_; ++t) {
    const int p = t & 1;
    // ---- stage this XCD's replica for step t (S_{t-1} | x_t)
    stage_and_wait(t, tid, xcd, rank, cnt, pubH, pubX, repH_x, repX_x, sync_);

    bf16_t* repHs = repH_x + (size_t)p * ((size_t)256*2048);
    bf16_t* repXs = repX_x + (size_t)p * ((size_t)256*512);

    // ---- phase B: per-wave GEMM over K-half, counted-vmcnt reg pipeline
    WAIT_VM0();
    f32x4 acc = {0.f, 0.f, 0.f, 0.f};
    bf16x8 pb[4];
    {
      const int arow = rbase + rt*16 + fl;
      const char* aH = reinterpret_cast<const char*>(repHs) + (size_t)arow*4096 + kg*16;
      const char* aX = reinterpret_cast<const char*>(repXs) + (size_t)arow*1024 + kg*16;
      const int cb0 = kh * 40;
      auto cptr = [&](int cc) -> const char* {
        return cc < 64 ? aH + cc*64 : aX + (cc - 64)*64;
      };
      ld_sc0_x4(pb[0], cptr(cb0 + 0));
      ld_sc0_x4(pb[1], cptr(cb0 + 1));
      ld_sc0_x4(pb[2], cptr(cb0 + 2));
      ld_sc0_x4(pb[3], cptr(cb0 + 3));
      #pragma unroll 4
      for (int c = 0; c < 36; ++c) {
        WAIT_VM(3);
        const int cc = cb0 + c;
        acc = MFMA16(pb[c & 3], Wl[(cc*4 + kg)*16 + fl], acc);
        ld_sc0_x4(pb[c & 3], cptr(cc + 4));
      }
      WAIT_VM(3); acc = MFMA16(pb[0], Wl[((cb0+36)*4 + kg)*16 + fl], acc);
      WAIT_VM(2); acc = MFMA16(pb[1], Wl[((cb0+37)*4 + kg)*16 + fl], acc);
      WAIT_VM(1); acc = MFMA16(pb[2], Wl[((cb0+38)*4 + kg)*16 + fl], acc);
      WAIT_VM(0); acc = MFMA16(pb[3], Wl[((cb0+39)*4 + kg)*16 + fl], acc);
    }

    // ---- phase C: K-half reduce (padded Scr), gate, transpose to Ts
    if (kh == 1) {
      #pragma unroll
      for (int j = 0; j < 4; ++j)
        Scr[rt*272 + (kg*4 + j)*17 + fl] = acc[j];
    }
    __syncthreads();                       // all phase-B reads complete here
    if (tid == 0) bump(s_dnb(sync_, xcd, p));
    if (kh == 0) {
      #pragma unroll
      for (int j = 0; j < 4; ++j) {
        const float v = acc[j] + Scr[rt*272 + (kg*4 + j)*17 + fl];
        const float o = gi * hr[j] + sav * tanhf(v + bias);
        hr[j] = o;
        Ts[(rt*16 + kg*4 + j)*16 + fl] = (bf16_t)o;
        if (t == T_ - 1)
          out[(size_t)T_*B_*NO_ + (size_t)(rbase + rt*16 + kg*4 + j)*NH_ + col_g] = o;
      }
    }
    __syncthreads();

    // ---- phase D: publish S_t (pub slot (t+1)&1) + x_{t+1}, drain, flag
    {
      const int r = tid >> 3, q = tid & 7;
      const unsigned v = *reinterpret_cast<const unsigned*>(&Ts[r*16 + q*2]);
      st_sc01_u32(pubH + (size_t)((t+1)&1)*(256*4096) + (size_t)bid*4096 + r*32 + q*4, v);
    }
    if (t + 1 < T_ && tid < 256) {
      const int r = tid >> 1, pr = tid & 1;
      const float* xs = x + ((size_t)(rbase + r)*T_ + (t+1))*NI_ + cg*4 + pr*2;
      union { unsigned u; bf16_t h2[2]; } pk;
      pk.h2[0] = (bf16_t)xs[0]; pk.h2[1] = (bf16_t)xs[1];
      st_sc01_u32(pubX + (size_t)((t+1)&1)*(256*1024) + (size_t)bid*1024 + r*8 + pr*4, pk.u);
    }
    WAIT_VM0();
    __syncthreads();
    if (tid == 0) bump(s_flg(sync_, bid));

    // ---- phase E: decoder y_{t-2} from replica slot (t-1)&1 (off critical path)
    if (t >= 2)
      dec_tile(bid, tid, repH_x + (size_t)((t-1) & 1)*((size_t)256*2048),
               Wdec, b_dec, out + (size_t)(t-2)*B_*NO_, Scr);
    if (tid == 0 && t >= 1) bump(s_dnd(sync_, xcd, (t-1) & 1));  // t==1: dummy for slot 0
  }

  // ---- epilogue: y_{T-2} from slot 1; stage(512) S_{T-1} -> slot 0; y_{T-1}
  dec_tile(bid, tid, repH_x + (size_t)1*((size_t)256*2048), Wdec, b_dec,
           out + (size_t)(T_-2)*B_*NO_, Scr);
  stage_and_wait(T_, tid, xcd, rank, cnt, pubH, pubX, repH_x, repX_x, sync_);
  dec_tile(bid, tid, repH_x, Wdec, b_dec, out + (size_t)(T_-1)*B_*NO_, Scr);
}

extern "C" void kernel_launch(void* const* d_in, const int* in_sizes, int n_in,
                              void* d_out, int out_size, void* d_ws, size_t ws_size,
                              hipStream_t stream) {
  const float* x     = (const float*)d_in[0];
  const float* dt_p  = (const float*)d_in[1];
  const float* a_p   = (const float*)d_in[2];
  const float* W_enc = (const float*)d_in[3];
  const float* b_enc = (const float*)d_in[4];
  const float* W_rec = (const float*)d_in[5];
  const float* b_rec = (const float*)d_in[6];
  const float* W_dec = (const float*)d_in[7];
  const float* b_dec = (const float*)d_in[8];
  float* out = (float*)d_out;

  char* p = (char*)d_ws;
  char*   pubH   = p;            p += (size_t)2*256*4096;            // 2MB
  char*   pubX   = p;            p += (size_t)2*256*1024;            // 512KB
  bf16_t* repH   = (bf16_t*)p;   p += (size_t)8*2*256*2048*2;        // 16MB
  bf16_t* repX   = (bf16_t*)p;   p += (size_t)8*2*256*512*2;         // 4MB
  bf16_t* Wdec_b = (bf16_t*)p;   p += (size_t)NO_*NH_*2;             // 1MB
  int*    sync_  = (int*)p;      p += 5120*4;                        // 20KB (~23.6MB)

  hipMemsetAsync(sync_, 0, 5120*4, stream);

  k_cvt<<<64, 256, 0, stream>>>(W_dec, Wdec_b, NO_ * NH_);

  k_prnn<<<dim3(256), dim3(1024), 0, stream>>>(
      x, dt_p, a_p, W_rec, W_enc, Wdec_b, b_rec, b_enc, b_dec,
      pubH, pubX, repH, repX, sync_, out);
}

// Round 10
// 13433.736 us; speedup vs baseline: 1.2701x; 1.2701x over previous
//
#include <hip/hip_runtime.h>
#include <hip/hip_bf16.h>
#include <math.h>

// PRNN round 10: 2D XCD partition (row-group x col-side), no-inv coherence.
// XCD (rg, side): rows rg*64..+64, cols side*1024..+1024. Each of its 32 CUs:
// 64 rows x 32 cols, FULL composite K=2560 (no split-K). W_rec slice (32 cols x
// 2048) LDS-resident (128 KB). Per step: GEMM from local L2 (sc0 loads of h),
// gate in-register (f32 master in VGPRs), publish own 128 KB h-half to the row
// partner via sc0sc1, mirror partner's 128 KB into local L2. NO acquire-inv and
// NO wbl2 anywhere => read-only data (W_enc,W_dec,x,biases) stays L2-warm.
// Flags: relaxed agent-scope monotone counters (r9-proven primitives).
// Decoder y lagged 2 steps (depth-4 local ring), off critical path.
// y_t = h_t@Wdec^T + b_dec ; h_t = (1-s)h_{t-1} + s*a*tanh(x_t@Wenc^T + b_enc + h_{t-1}@Wrec^T + b_rec)

#define B_   256
#define T_   512
#define NI_  512
#define NH_  2048
#define NO_  256

typedef __bf16 bf16_t;
typedef __bf16 bf16x8 __attribute__((ext_vector_type(8)));
typedef float  f32x4  __attribute__((ext_vector_type(4)));

#define MFMA16(a,b,c) __builtin_amdgcn_mfma_f32_16x16x32_bf16((a),(b),(c),0,0,0)
#define XCC_HWREG_IMM (20 | (31 << 11))

__device__ __forceinline__ void ld_sc0_x4(bf16x8& d, const void* p) {
  asm volatile("global_load_dwordx4 %0, %1, off sc0" : "=v"(d) : "v"(p));
}
__device__ __forceinline__ void ld_sc01_u32(unsigned& d, const void* p) {
  asm volatile("global_load_dword %0, %1, off sc0 sc1" : "=v"(d) : "v"(p));
}
__device__ __forceinline__ void st_sc01_u32(void* p, unsigned v) {
  asm volatile("global_store_dword %0, %1, off sc0 sc1" :: "v"(p), "v"(v));
}
#define WAIT_VM0() do { asm volatile("s_waitcnt vmcnt(0)" ::: "memory"); \
                        __builtin_amdgcn_sched_barrier(0); } while (0)
#define WAIT_VM(n) do { asm volatile("s_waitcnt vmcnt(" #n ")" ::: "memory"); \
                        __builtin_amdgcn_sched_barrier(0); } while (0)

__device__ __forceinline__ void spin_ge(int* p, int tgt) {
  while (__hip_atomic_load(p, __ATOMIC_RELAXED, __HIP_MEMORY_SCOPE_AGENT) < tgt)
    __builtin_amdgcn_s_sleep(4);
}
__device__ __forceinline__ void bump(int* p) {
  __hip_atomic_fetch_add(p, 1, __ATOMIC_RELAXED, __HIP_MEMORY_SCOPE_AGENT);
}

// sync layout (64B-strided ints)
__device__ __forceinline__ int* s_floc(int* s, int x)  { return s + x*16; }
__device__ __forceinline__ int* s_fmir(int* s, int x)  { return s + 128 + x*16; }
__device__ __forceinline__ int* s_fpub(int* s, int i)  { return s + 256 + i*16; }
__device__ __forceinline__ int* s_reg(int* s, int x)   { return s + 384 + x*16; }
__device__ __forceinline__ int* s_start(int* s)        { return s + 512; }

__global__ __launch_bounds__(256) void k_cvt(const float* __restrict__ src,
                                             bf16_t* __restrict__ dst, int n) {
  int i = blockIdx.x * 256 + threadIdx.x;
  const int stride = gridDim.x * 256;
  for (; i < n; i += stride) dst[i] = (bf16_t)src[i];
}

// Decoder: 16x16 y-tile (rows rg*64 + side*32 + (rank>>4)*16, cols (rank&15)*16),
// K=2048 over 16 waves; h from local hloc/hmir slot (sc0); Wdec L2-warm.
__device__ __forceinline__ void dec_tile(
    int tid, int side, int rank, int rg,
    const bf16_t* hl, const bf16_t* hm,
    const bf16_t* __restrict__ Wdec, const float* __restrict__ b_dec,
    float* __restrict__ y_out, float* Scr)
{
  const int lane = tid & 63, w = tid >> 6, fl = lane & 15, kg = lane >> 4;
  const int drl = side*32 + (rank >> 4)*16;   // local row base (0..63)
  const int dc  = (rank & 15) * 16;           // y col base
  const bf16_t* hbase = ((w >> 3) == side) ? hl : hm;
  const int kb = (w & 7) * 128;               // offset within col-half
  bf16x8 hf[4];
  #pragma unroll
  for (int i = 0; i < 4; ++i)
    ld_sc0_x4(hf[i], hbase + (size_t)(drl + fl)*1024 + kb + i*32 + kg*8);
  WAIT_VM0();
  f32x4 d = {0.f, 0.f, 0.f, 0.f};
  #pragma unroll
  for (int i = 0; i < 4; ++i) {
    bf16x8 wf = *reinterpret_cast<const bf16x8*>(
        Wdec + (size_t)(dc + fl)*NH_ + w*128 + i*32 + kg*8);
    d = MFMA16(hf[i], wf, d);
  }
  __syncthreads();
  #pragma unroll
  for (int j = 0; j < 4; ++j) Scr[w*256 + (kg*4 + j)*16 + fl] = d[j];
  __syncthreads();
  if (tid < 256) {
    const int r = tid >> 4, c = tid & 15;
    float s = b_dec[dc + c];
    #pragma unroll
    for (int ww = 0; ww < 16; ++ww) s += Scr[ww*256 + r*16 + c];
    y_out[(size_t)(rg*64 + drl + r)*NO_ + dc + c] = s;
  }
}

__global__ __launch_bounds__(1024, 1) void k_prnn(
    const float* __restrict__ x,
    const float* __restrict__ dt_p, const float* __restrict__ a_p,
    const float* __restrict__ Wrec,
    const bf16_t* __restrict__ Wenc_b, const bf16_t* __restrict__ Wdec_b,
    const float* __restrict__ b_rec, const float* __restrict__ b_enc,
    const float* __restrict__ b_dec,
    bf16_t* __restrict__ hloc, bf16_t* __restrict__ hmir,
    bf16_t* __restrict__ pub, int* __restrict__ sync_,
    float* __restrict__ out)
{
  __shared__ alignas(16) bf16x8 Wl[256 * 32];  // 128KB: [K-granule 0..255][col 0..31]
  __shared__ alignas(16) float  Scr[6144];     // 24KB: K-quarter reduce / dec scratch
  __shared__ alignas(16) bf16_t Ts[2048];      // 4KB:  h-tile for coalesced stores
  __shared__ int sh_xcd, sh_rank;

  const int tid  = threadIdx.x;
  const int lane = tid & 63;
  const int fl   = lane & 15;
  const int kg   = lane >> 4;
  const int w    = tid >> 6;   // wave 0..15
  const int rt   = w & 3;      // row tile (16 rows)
  const int kq   = w >> 2;     // K quarter (640)

  // ---- registration (r9-proven): physical XCD, local rank
  if (tid == 0) {
    const int xc = (int)(__builtin_amdgcn_s_getreg(XCC_HWREG_IMM) & 7u);
    const int rk = __hip_atomic_fetch_add(s_reg(sync_, xc), 1,
                     __ATOMIC_RELAXED, __HIP_MEMORY_SCOPE_AGENT);
    bump(s_start(sync_));
    spin_ge(s_start(sync_), 256);
    sh_xcd = xc; sh_rank = rk;
  }
  __syncthreads();
  const int xcd = sh_xcd, rank = sh_rank;
  if (rank >= 32) return;            // empirically never (1 WG/CU); miss => loud hang
  const int rg = xcd >> 1, side = xcd & 1;

  bf16_t* hloc_x = hloc + (size_t)xcd * 4 * 65536;
  bf16_t* hmir_x = hmir + (size_t)xcd * 4 * 65536;
  bf16_t* pub_own = pub + (size_t)(rg*2 + side)   * 2 * 65536;
  bf16_t* pub_par = pub + (size_t)(rg*2 + (side^1)) * 2 * 65536;
  int* floc = s_floc(sync_, xcd);
  int* fmir = s_fmir(sync_, xcd);
  int* fpub_o = s_fpub(sync_, rg*2 + side);
  int* fpub_p = s_fpub(sync_, rg*2 + (side^1));

  const float sgate = 1.f / (1.f + expf(-dt_p[0]));
  const float av = a_p[0];
  const float gi = 1.f - sgate;
  const float sav = sgate * av;
  const int colbase = rank * 32;
  const int colg0 = side*1024 + colbase + fl;
  const int colg1 = colg0 + 16;
  const float bias0 = b_rec[colg0] + b_enc[colg0];
  const float bias1 = b_rec[colg1] + b_enc[colg1];
  const bf16_t* we0 = Wenc_b + (size_t)colg0 * NI_;
  const bf16_t* we1 = Wenc_b + (size_t)colg1 * NI_;
  const int lrow = rt*16 + fl;               // local A row (0..63)
  const int grow = rg*64 + lrow;             // global batch row

  // f32 master state (kq==0 waves): rows rt*16+kg*4+j, cols {colg0, colg1}
  f32x4 hr0 = {0.f,0.f,0.f,0.f}, hr1 = {0.f,0.f,0.f,0.f};

  // ---- prologue: W_rec slice (32 cols x 2048) -> LDS [granule][col]
  {
    const int c = tid >> 5, part = tid & 31;
    const int cglob = side*1024 + colbase + c;
    #pragma unroll
    for (int i = 0; i < 8; ++i) {
      const int g = part*8 + i;              // 0..255
      const float* src = Wrec + (size_t)cglob * NH_ + g*8;
      float4 f0 = reinterpret_cast<const float4*>(src)[0];
      float4 f1 = reinterpret_cast<const float4*>(src)[1];
      bf16x8 w8 = {(bf16_t)f0.x, (bf16_t)f0.y, (bf16_t)f0.z, (bf16_t)f0.w,
                   (bf16_t)f1.x, (bf16_t)f1.y, (bf16_t)f1.z, (bf16_t)f1.w};
      Wl[g*32 + c] = w8;
    }
  }
  __syncthreads();

  #pragma unroll 1
  for (int t = 0; t < T_; ++t) {
    const int slotR = (t + 3) & 3;           // S_{t-1}
    const int slotW = t & 3;                 // S_t
    const int pslot = t & 1;

    // ---- entry: S_{t-1} fully written (local gates + mirror)
    if (tid == 0)  spin_ge(floc, 32*t);
    if (tid == 64) spin_ge(fmir, 32*t);
    __syncthreads();

    const bf16_t* hl = hloc_x + (size_t)slotR * 65536;
    const bf16_t* hm = hmir_x + (size_t)slotR * 65536;

    // ---- GEMM: wave (rt,kq) does 16 rows x 32 cols over K-quarter 640
    f32x4 acc0 = {0.f,0.f,0.f,0.f}, acc1 = {0.f,0.f,0.f,0.f};
    const int kbase = kq * 640;
    if (kq < 3) {
      bf16x8 pa[4];
      auto aptr = [&](int c) -> const bf16_t* {
        const int k = kbase + c*32;
        const bf16_t* b = ((k >> 10) == side) ? hl : hm;
        return b + (size_t)lrow*1024 + (k & 1023) + kg*8;
      };
      ld_sc0_x4(pa[0], aptr(0)); ld_sc0_x4(pa[1], aptr(1));
      ld_sc0_x4(pa[2], aptr(2)); ld_sc0_x4(pa[3], aptr(3));
      #pragma unroll 4
      for (int c = 0; c < 16; ++c) {
        WAIT_VM(3);
        const int gg = kbase/8 + c*4 + kg;
        acc0 = MFMA16(pa[c & 3], Wl[gg*32 + fl], acc0);
        acc1 = MFMA16(pa[c & 3], Wl[gg*32 + 16 + fl], acc1);
        ld_sc0_x4(pa[c & 3], aptr(c + 4));
      }
      #pragma unroll
      for (int c = 16; c < 20; ++c) {
        switch (19 - c) { case 3: WAIT_VM(3); break; case 2: WAIT_VM(2); break;
                          case 1: WAIT_VM(1); break; default: WAIT_VM0(); }
        const int gg = kbase/8 + c*4 + kg;
        acc0 = MFMA16(pa[c & 3], Wl[gg*32 + fl], acc0);
        acc1 = MFMA16(pa[c & 3], Wl[gg*32 + 16 + fl], acc1);
      }
    } else {
      // h chunks: K 1920..2048 (half 1)
      const bf16_t* bh = (1 == side) ? hl : hm;
      bf16x8 pa[4];
      #pragma unroll
      for (int c = 0; c < 4; ++c)
        ld_sc0_x4(pa[c], bh + (size_t)lrow*1024 + ((1920 + c*32) & 1023) + kg*8);
      #pragma unroll
      for (int c = 0; c < 4; ++c) {
        switch (3 - c) { case 3: WAIT_VM(3); break; case 2: WAIT_VM(2); break;
                         case 1: WAIT_VM(1); break; default: WAIT_VM0(); }
        const int gg = 240 + c*4 + kg;
        acc0 = MFMA16(pa[c], Wl[gg*32 + fl], acc0);
        acc1 = MFMA16(pa[c], Wl[gg*32 + 16 + fl], acc1);
      }
      // x chunks: K' 0..512 (f32, L2-cached; Wenc_b B-frags L2-warm)
      const float* xrow = x + ((size_t)grow * T_ + t) * NI_;
      #pragma unroll 4
      for (int c = 0; c < 16; ++c) {
        const int kp = c*32 + kg*8;
        float4 u = *reinterpret_cast<const float4*>(xrow + kp);
        float4 v = *reinterpret_cast<const float4*>(xrow + kp + 4);
        bf16x8 a = {(bf16_t)u.x, (bf16_t)u.y, (bf16_t)u.z, (bf16_t)u.w,
                    (bf16_t)v.x, (bf16_t)v.y, (bf16_t)v.z, (bf16_t)v.w};
        bf16x8 b0 = *reinterpret_cast<const bf16x8*>(we0 + kp);
        bf16x8 b1 = *reinterpret_cast<const bf16x8*>(we1 + kp);
        acc0 = MFMA16(a, b0, acc0);
        acc1 = MFMA16(a, b1, acc1);
      }
    }

    // ---- K-quarter reduce + gate (kq0 waves hold master state)
    __syncthreads();
    if (kq != 0) {
      const int base = (kq - 1)*2048 + rt*16*32;
      #pragma unroll
      for (int j = 0; j < 4; ++j) {
        Scr[base + (kg*4 + j)*32 + fl]      = acc0[j];
        Scr[base + (kg*4 + j)*32 + 16 + fl] = acc1[j];
      }
    }
    __syncthreads();
    if (kq == 0) {
      #pragma unroll
      for (int j = 0; j < 4; ++j) {
        const int ri = (rt*16 + kg*4 + j)*32;
        const float v0 = acc0[j] + Scr[ri + fl] + Scr[2048 + ri + fl] + Scr[4096 + ri + fl];
        const float v1 = acc1[j] + Scr[ri + 16 + fl] + Scr[2048 + ri + 16 + fl] + Scr[4096 + ri + 16 + fl];
        const float o0 = gi*hr0[j] + sav*tanhf(v0 + bias0);
        const float o1 = gi*hr1[j] + sav*tanhf(v1 + bias1);
        hr0[j] = o0; hr1[j] = o1;
        Ts[(rt*16 + kg*4 + j)*32 + fl]      = (bf16_t)o0;
        Ts[(rt*16 + kg*4 + j)*32 + 16 + fl] = (bf16_t)o1;
        if (t == T_ - 1) {   // exact f32 final h from register master
          float* hd = out + (size_t)T_*B_*NO_ + (size_t)(rg*64 + rt*16 + kg*4 + j)*NH_;
          hd[colg0] = o0; hd[colg1] = o1;
        }
      }
    }
    __syncthreads();

    // ---- store own tile: hloc (plain, local L2) + pub (sc0sc1, for partner)
    {
      const int r = tid >> 4, q = tid & 15;
      const unsigned dv = *reinterpret_cast<const unsigned*>(&Ts[r*32 + q*2]);
      const int off = r*1024 + colbase + q*2;
      *reinterpret_cast<unsigned*>(hloc_x + (size_t)slotW*65536 + off) = dv;
      st_sc01_u32(pub_own + (size_t)pslot*65536 + off, dv);
      WAIT_VM0();
    }
    __syncthreads();
    if (tid == 0) { bump(floc); bump(fpub_o); }

    // ---- mirror partner half into local L2 (each WG stages its 4KB col slice)
    if (tid == 0) spin_ge(fpub_p, 32*(t + 1));
    __syncthreads();
    {
      const int r = tid >> 4, q = tid & 15;
      const int off = r*1024 + colbase + q*2;
      unsigned mv;
      ld_sc01_u32(mv, pub_par + (size_t)pslot*65536 + off);
      WAIT_VM0();
      *reinterpret_cast<unsigned*>(hmir_x + (size_t)slotW*65536 + off) = mv;
    }
    __syncthreads();             // drains mirror stores (vmcnt before barrier)
    if (tid == 0) bump(fmir);

    // ---- decoder y_{t-2} from slot (t-2)&3 (off critical path; slot is
    // rewritten only at gate(t+2), which transitively follows my fmir(t+1) bump,
    // which follows this dec in program order)
    if (t >= 2)
      dec_tile(tid, side, rank, rg,
               hloc_x + (size_t)((t + 2) & 3)*65536,
               hmir_x + (size_t)((t + 2) & 3)*65536,
               Wdec_b, b_dec, out + (size_t)(t - 2)*B_*NO_, Scr);
  }

  // ---- epilogue: y_{T-2} (slot 2) and y_{T-1} (slot 3)
  if (tid == 0)  spin_ge(floc, 32*T_);
  if (tid == 64) spin_ge(fmir, 32*T_);
  __syncthreads();
  dec_tile(tid, side, rank, rg, hloc_x + (size_t)2*65536, hmir_x + (size_t)2*65536,
           Wdec_b, b_dec, out + (size_t)(T_ - 2)*B_*NO_, Scr);
  dec_tile(tid, side, rank, rg, hloc_x + (size_t)3*65536, hmir_x + (size_t)3*65536,
           Wdec_b, b_dec, out + (size_t)(T_ - 1)*B_*NO_, Scr);
}

extern "C" void kernel_launch(void* const* d_in, const int* in_sizes, int n_in,
                              void* d_out, int out_size, void* d_ws, size_t ws_size,
                              hipStream_t stream) {
  const float* x     = (const float*)d_in[0];
  const float* dt_p  = (const float*)d_in[1];
  const float* a_p   = (const float*)d_in[2];
  const float* W_enc = (const float*)d_in[3];
  const float* b_enc = (const float*)d_in[4];
  const float* W_rec = (const float*)d_in[5];
  const float* b_rec = (const float*)d_in[6];
  const float* W_dec = (const float*)d_in[7];
  const float* b_dec = (const float*)d_in[8];
  float* out = (float*)d_out;

  char* p = (char*)d_ws;
  bf16_t* hloc   = (bf16_t*)p;  p += (size_t)8*4*65536*2;   // 4MB
  bf16_t* hmir   = (bf16_t*)p;  p += (size_t)8*4*65536*2;   // 4MB
  bf16_t* pub    = (bf16_t*)p;  p += (size_t)8*2*65536*2;   // 2MB
  bf16_t* Wenc_b = (bf16_t*)p;  p += (size_t)NH_*NI_*2;     // 2MB
  bf16_t* Wdec_b = (bf16_t*)p;  p += (size_t)NO_*NH_*2;     // 1MB
  int*    sync_  = (int*)p;     p += 8192;                  // 8KB (~13MB total)

  hipMemsetAsync(hloc, 0, (size_t)8*4*65536*2, stream);     // slot 3 = S_{-1} = 0
  hipMemsetAsync(hmir, 0, (size_t)8*4*65536*2, stream);
  hipMemsetAsync(sync_, 0, 8192, stream);

  k_cvt<<<128, 256, 0, stream>>>(W_enc, Wenc_b, NH_ * NI_);
  k_cvt<<<64, 256, 0, stream>>>(W_dec, Wdec_b, NO_ * NH_);

  k_prnn<<<dim3(256), dim3(1024), 0, stream>>>(
      x, dt_p, a_p, W_rec, Wenc_b, Wdec_b, b_rec, b_enc, b_dec,
      hloc, hmir, pub, sync_, out);
}

// Round 12
// 12994.200 us; speedup vs baseline: 1.3131x; 1.0338x over previous
//
#include <hip/hip_runtime.h>
#include <hip/hip_bf16.h>
#include <math.h>

// PRNN round 12: r10 exactly, except (a) the three contended per-XCD counters are
// replaced by per-WG single-writer flag arrays (signal = ONE uncontended agent
// fetch_add per WG; polls = 32 parallel lanes), (b) mirror needs only the
// partner's rank-matched flag, (c) decoder runs between publish and mirror so
// its MFMA time hides the partner publish latency. All data paths, ring depths,
// GEMM, and the registration protocol are byte-for-byte r10 (passed, 13.4ms).
// y_t = h_t@Wdec^T + b_dec ; h_t = (1-s)h_{t-1} + s*a*tanh(x_t@Wenc^T + b_enc + h_{t-1}@Wrec^T + b_rec)

#define B_   256
#define T_   512
#define NI_  512
#define NH_  2048
#define NO_  256

typedef __bf16 bf16_t;
typedef __bf16 bf16x8 __attribute__((ext_vector_type(8)));
typedef float  f32x4  __attribute__((ext_vector_type(4)));

#define MFMA16(a,b,c) __builtin_amdgcn_mfma_f32_16x16x32_bf16((a),(b),(c),0,0,0)
#define XCC_HWREG_IMM (20 | (31 << 11))

__device__ __forceinline__ void ld_sc0_x4(bf16x8& d, const void* p) {
  asm volatile("global_load_dwordx4 %0, %1, off sc0" : "=v"(d) : "v"(p));
}
__device__ __forceinline__ void ld_sc01_u32(unsigned& d, const void* p) {
  asm volatile("global_load_dword %0, %1, off sc0 sc1" : "=v"(d) : "v"(p));
}
__device__ __forceinline__ void st_sc01_u32(void* p, unsigned v) {
  asm volatile("global_store_dword %0, %1, off sc0 sc1" :: "v"(p), "v"(v));
}
#define WAIT_VM0() do { asm volatile("s_waitcnt vmcnt(0)" ::: "memory"); \
                        __builtin_amdgcn_sched_barrier(0); } while (0)
#define WAIT_VM(n) do { asm volatile("s_waitcnt vmcnt(" #n ")" ::: "memory"); \
                        __builtin_amdgcn_sched_barrier(0); } while (0)

__device__ __forceinline__ void spin_ge(int* p, int tgt) {
  while (__hip_atomic_load(p, __ATOMIC_RELAXED, __HIP_MEMORY_SCOPE_AGENT) < tgt)
    __builtin_amdgcn_s_sleep(2);
}
__device__ __forceinline__ void bump(int* p) {
  __hip_atomic_fetch_add(p, 1, __ATOMIC_RELAXED, __HIP_MEMORY_SCOPE_AGENT);
}

// per-WG flag arrays (64B-strided ints)
__device__ __forceinline__ int* fA_loc(int* s, int x, int r) { return s + (x*32 + r)*16; }
__device__ __forceinline__ int* fA_mir(int* s, int x, int r) { return s + 4096 + (x*32 + r)*16; }
__device__ __forceinline__ int* fA_pub(int* s, int x, int r) { return s + 8192 + (x*32 + r)*16; }

__global__ __launch_bounds__(256) void k_cvt(const float* __restrict__ src,
                                             bf16_t* __restrict__ dst, int n) {
  int i = blockIdx.x * 256 + threadIdx.x;
  const int stride = gridDim.x * 256;
  for (; i < n; i += stride) dst[i] = (bf16_t)src[i];
}

// Decoder: 16x16 y-tile (rows rg*64 + side*32 + (rank>>4)*16, cols (rank&15)*16),
// K=2048 over 16 waves; h from local hloc/hmir slot (sc0); Wdec L2-warm. (r10)
__device__ __forceinline__ void dec_tile(
    int tid, int side, int rank, int rg,
    const bf16_t* hl, const bf16_t* hm,
    const bf16_t* __restrict__ Wdec, const float* __restrict__ b_dec,
    float* __restrict__ y_out, float* Scr)
{
  const int lane = tid & 63, w = tid >> 6, fl = lane & 15, kg = lane >> 4;
  const int drl = side*32 + (rank >> 4)*16;
  const int dc  = (rank & 15) * 16;
  const bf16_t* hbase = ((w >> 3) == side) ? hl : hm;
  const int kb = (w & 7) * 128;
  bf16x8 hf[4];
  #pragma unroll
  for (int i = 0; i < 4; ++i)
    ld_sc0_x4(hf[i], hbase + (size_t)(drl + fl)*1024 + kb + i*32 + kg*8);
  WAIT_VM0();
  f32x4 d = {0.f, 0.f, 0.f, 0.f};
  #pragma unroll
  for (int i = 0; i < 4; ++i) {
    bf16x8 wf = *reinterpret_cast<const bf16x8*>(
        Wdec + (size_t)(dc + fl)*NH_ + w*128 + i*32 + kg*8);
    d = MFMA16(hf[i], wf, d);
  }
  __syncthreads();
  #pragma unroll
  for (int j = 0; j < 4; ++j) Scr[w*256 + (kg*4 + j)*16 + fl] = d[j];
  __syncthreads();
  if (tid < 256) {
    const int r = tid >> 4, c = tid & 15;
    float s = b_dec[dc + c];
    #pragma unroll
    for (int ww = 0; ww < 16; ++ww) s += Scr[ww*256 + r*16 + c];
    y_out[(size_t)(rg*64 + drl + r)*NO_ + dc + c] = s;
  }
}

__global__ __launch_bounds__(1024, 1) void k_prnn(
    const float* __restrict__ x,
    const float* __restrict__ dt_p, const float* __restrict__ a_p,
    const float* __restrict__ Wrec,
    const bf16_t* __restrict__ Wenc_b, const bf16_t* __restrict__ Wdec_b,
    const float* __restrict__ b_rec, const float* __restrict__ b_enc,
    const float* __restrict__ b_dec,
    bf16_t* __restrict__ hloc, bf16_t* __restrict__ hmir,
    bf16_t* __restrict__ pub, int* __restrict__ sync_,
    float* __restrict__ out)
{
  __shared__ alignas(16) bf16x8 Wl[256 * 32];  // 128KB: [K-granule][col]
  __shared__ alignas(16) float  Scr[6144];     // 24KB: reduce / dec scratch
  __shared__ alignas(16) bf16_t Ts[2048];      // 4KB:  h-tile for coalesced stores
  __shared__ int sh_xcd, sh_rank;

  const int tid  = threadIdx.x;
  const int lane = tid & 63;
  const int fl   = lane & 15;
  const int kg   = lane >> 4;
  const int w    = tid >> 6;   // wave 0..15
  const int rt   = w & 3;      // row tile (16 rows)
  const int kq   = w >> 2;     // K quarter (640)

  // ---- registration (r9/r10-proven)
  if (tid == 0) {
    const int xc = (int)(__builtin_amdgcn_s_getreg(XCC_HWREG_IMM) & 7u);
    int* reg = sync_ + 12288 + xc * 16;
    const int rk = __hip_atomic_fetch_add(reg, 1, __ATOMIC_RELAXED, __HIP_MEMORY_SCOPE_AGENT);
    __hip_atomic_fetch_add(sync_ + 12416, 1, __ATOMIC_RELAXED, __HIP_MEMORY_SCOPE_AGENT);
    spin_ge(sync_ + 12416, 256);
    sh_xcd = xc; sh_rank = rk;
  }
  __syncthreads();
  const int xcd = sh_xcd, rank = sh_rank;
  if (rank >= 32) return;            // 1 WG/CU dispatch (r10-proven); else loud hang
  const int rg = xcd >> 1, side = xcd & 1;

  bf16_t* hloc_x = hloc + (size_t)xcd * 4 * 65536;
  bf16_t* hmir_x = hmir + (size_t)xcd * 4 * 65536;
  bf16_t* pub_own = pub + (size_t)xcd * 2 * 65536;
  bf16_t* pub_par = pub + (size_t)(xcd ^ 1) * 2 * 65536;

  const float sgate = 1.f / (1.f + expf(-dt_p[0]));
  const float av = a_p[0];
  const float gi = 1.f - sgate;
  const float sav = sgate * av;
  const int colbase = rank * 32;
  const int colg0 = side*1024 + colbase + fl;
  const int colg1 = colg0 + 16;
  const float bias0 = b_rec[colg0] + b_enc[colg0];
  const float bias1 = b_rec[colg1] + b_enc[colg1];
  const bf16_t* we0 = Wenc_b + (size_t)colg0 * NI_;
  const bf16_t* we1 = Wenc_b + (size_t)colg1 * NI_;
  const int lrow = rt*16 + fl;               // local A row (0..63)
  const int grow = rg*64 + lrow;             // global batch row

  f32x4 hr0 = {0.f,0.f,0.f,0.f}, hr1 = {0.f,0.f,0.f,0.f};  // master state (kq0)

  // ---- prologue: W_rec slice (32 cols x 2048) -> LDS [granule][col]  (r10)
  {
    const int c = tid >> 5, part = tid & 31;
    const int cglob = side*1024 + colbase + c;
    #pragma unroll
    for (int i = 0; i < 8; ++i) {
      const int g = part*8 + i;              // 0..255
      const float* src = Wrec + (size_t)cglob * NH_ + g*8;
      float4 f0 = reinterpret_cast<const float4*>(src)[0];
      float4 f1 = reinterpret_cast<const float4*>(src)[1];
      bf16x8 w8 = {(bf16_t)f0.x, (bf16_t)f0.y, (bf16_t)f0.z, (bf16_t)f0.w,
                   (bf16_t)f1.x, (bf16_t)f1.y, (bf16_t)f1.z, (bf16_t)f1.w};
      Wl[g*32 + c] = w8;
    }
  }
  __syncthreads();

  #pragma unroll 1
  for (int t = 0; t < T_; ++t) {
    const int slotR = (t + 3) & 3;           // S_{t-1}
    const int slotW = t & 3;                 // S_t
    const int pslot = t & 1;

    // ---- entry: S_{t-1} fully written — 32 parallel polls on floc + fmir
    if (tid < 32)                    spin_ge(fA_loc(sync_, xcd, tid), t);
    else if (tid >= 64 && tid < 96)  spin_ge(fA_mir(sync_, xcd, tid - 64), t);
    __syncthreads();

    const bf16_t* hl = hloc_x + (size_t)slotR * 65536;
    const bf16_t* hm = hmir_x + (size_t)slotR * 65536;

    // ---- GEMM: wave (rt,kq) does 16 rows x 32 cols over K-quarter 640  (r10)
    f32x4 acc0 = {0.f,0.f,0.f,0.f}, acc1 = {0.f,0.f,0.f,0.f};
    const int kbase = kq * 640;
    if (kq < 3) {
      bf16x8 pa[4];
      auto aptr = [&](int c) -> const bf16_t* {
        const int k = kbase + c*32;
        const bf16_t* b = ((k >> 10) == side) ? hl : hm;
        return b + (size_t)lrow*1024 + (k & 1023) + kg*8;
      };
      ld_sc0_x4(pa[0], aptr(0)); ld_sc0_x4(pa[1], aptr(1));
      ld_sc0_x4(pa[2], aptr(2)); ld_sc0_x4(pa[3], aptr(3));
      #pragma unroll 4
      for (int c = 0; c < 16; ++c) {
        WAIT_VM(3);
        const int gg = kbase/8 + c*4 + kg;
        acc0 = MFMA16(pa[c & 3], Wl[gg*32 + fl], acc0);
        acc1 = MFMA16(pa[c & 3], Wl[gg*32 + 16 + fl], acc1);
        ld_sc0_x4(pa[c & 3], aptr(c + 4));
      }
      #pragma unroll
      for (int c = 16; c < 20; ++c) {
        switch (19 - c) { case 3: WAIT_VM(3); break; case 2: WAIT_VM(2); break;
                          case 1: WAIT_VM(1); break; default: WAIT_VM0(); }
        const int gg = kbase/8 + c*4 + kg;
        acc0 = MFMA16(pa[c & 3], Wl[gg*32 + fl], acc0);
        acc1 = MFMA16(pa[c & 3], Wl[gg*32 + 16 + fl], acc1);
      }
    } else {
      const bf16_t* bh = (1 == side) ? hl : hm;
      bf16x8 pa[4];
      #pragma unroll
      for (int c = 0; c < 4; ++c)
        ld_sc0_x4(pa[c], bh + (size_t)lrow*1024 + ((1920 + c*32) & 1023) + kg*8);
      #pragma unroll
      for (int c = 0; c < 4; ++c) {
        switch (3 - c) { case 3: WAIT_VM(3); break; case 2: WAIT_VM(2); break;
                         case 1: WAIT_VM(1); break; default: WAIT_VM0(); }
        const int gg = 240 + c*4 + kg;
        acc0 = MFMA16(pa[c], Wl[gg*32 + fl], acc0);
        acc1 = MFMA16(pa[c], Wl[gg*32 + 16 + fl], acc1);
      }
      const float* xrow = x + ((size_t)grow * T_ + t) * NI_;
      #pragma unroll 4
      for (int c = 0; c < 16; ++c) {
        const int kp = c*32 + kg*8;
        float4 u = *reinterpret_cast<const float4*>(xrow + kp);
        float4 v = *reinterpret_cast<const float4*>(xrow + kp + 4);
        bf16x8 a = {(bf16_t)u.x, (bf16_t)u.y, (bf16_t)u.z, (bf16_t)u.w,
                    (bf16_t)v.x, (bf16_t)v.y, (bf16_t)v.z, (bf16_t)v.w};
        bf16x8 b0 = *reinterpret_cast<const bf16x8*>(we0 + kp);
        bf16x8 b1 = *reinterpret_cast<const bf16x8*>(we1 + kp);
        acc0 = MFMA16(a, b0, acc0);
        acc1 = MFMA16(a, b1, acc1);
      }
    }

    // ---- K-quarter reduce + gate (r10)
    __syncthreads();
    if (kq != 0) {
      const int base = (kq - 1)*2048 + rt*16*32;
      #pragma unroll
      for (int j = 0; j < 4; ++j) {
        Scr[base + (kg*4 + j)*32 + fl]      = acc0[j];
        Scr[base + (kg*4 + j)*32 + 16 + fl] = acc1[j];
      }
    }
    __syncthreads();
    if (kq == 0) {
      #pragma unroll
      for (int j = 0; j < 4; ++j) {
        const int ri = (rt*16 + kg*4 + j)*32;
        const float v0 = acc0[j] + Scr[ri + fl] + Scr[2048 + ri + fl] + Scr[4096 + ri + fl];
        const float v1 = acc1[j] + Scr[ri + 16 + fl] + Scr[2048 + ri + 16 + fl]
                                 + Scr[4096 + ri + 16 + fl];
        const float o0 = gi*hr0[j] + sav*tanhf(v0 + bias0);
        const float o1 = gi*hr1[j] + sav*tanhf(v1 + bias1);
        hr0[j] = o0; hr1[j] = o1;
        Ts[(rt*16 + kg*4 + j)*32 + fl]      = (bf16_t)o0;
        Ts[(rt*16 + kg*4 + j)*32 + 16 + fl] = (bf16_t)o1;
        if (t == T_ - 1) {   // exact f32 final h from register master
          float* hd = out + (size_t)T_*B_*NO_ + (size_t)(rg*64 + rt*16 + kg*4 + j)*NH_;
          hd[colg0] = o0; hd[colg1] = o1;
        }
      }
    }
    __syncthreads();

    // ---- store own tile: hloc (plain, local L2) + pub (sc01, for partner) (r10)
    {
      const int r = tid >> 4, q = tid & 15;
      const unsigned dv = *reinterpret_cast<const unsigned*>(&Ts[r*32 + q*2]);
      const int off = r*1024 + colbase + q*2;
      *reinterpret_cast<unsigned*>(hloc_x + (size_t)slotW*65536 + off) = dv;
      st_sc01_u32(pub_own + (size_t)pslot*65536 + off, dv);
      WAIT_VM0();
    }
    __syncthreads();
    if (tid == 0)       bump(fA_loc(sync_, xcd, rank));      // uncontended RMW
    else if (tid == 64) bump(fA_pub(sync_, xcd, rank));      // uncontended RMW

    // ---- decoder y_{t-2} here: overlaps the partner's publish latency.
    // Reads slots (t+2)&3; local mirrors write slot t&3 (disjoint, mod-4 dist 2);
    // a peer's mirror of slot (t+2)&3 happens at its step t+2, which requires my
    // fmir bump of step t+1 — after this dec in program order. Safe.
    if (t >= 2)
      dec_tile(tid, side, rank, rg,
               hloc_x + (size_t)((t + 2) & 3)*65536,
               hmir_x + (size_t)((t + 2) & 3)*65536,
               Wdec_b, b_dec, out + (size_t)(t - 2)*B_*NO_, Scr);

    // ---- mirror partner half into local L2 (rank-matched 4KB slice; needs only
    // the partner WG with the same rank to have published)
    if (tid == 0) spin_ge(fA_pub(sync_, xcd ^ 1, rank), t + 1);
    __syncthreads();
    {
      const int r = tid >> 4, q = tid & 15;
      const int off = r*1024 + colbase + q*2;
      unsigned mv;
      ld_sc01_u32(mv, pub_par + (size_t)pslot*65536 + off);
      WAIT_VM0();
      *reinterpret_cast<unsigned*>(hmir_x + (size_t)slotW*65536 + off) = mv;
    }
    __syncthreads();             // drains mirror stores (vmcnt before barrier)
    if (tid == 0) bump(fA_mir(sync_, xcd, rank));
  }

  // ---- epilogue: y_{T-2} (slot 2) and y_{T-1} (slot 3)  (r10 structure)
  if (tid < 32)                    spin_ge(fA_loc(sync_, xcd, tid), T_);
  else if (tid >= 64 && tid < 96)  spin_ge(fA_mir(sync_, xcd, tid - 64), T_);
  __syncthreads();
  dec_tile(tid, side, rank, rg, hloc_x + (size_t)2*65536, hmir_x + (size_t)2*65536,
           Wdec_b, b_dec, out + (size_t)(T_ - 2)*B_*NO_, Scr);
  dec_tile(tid, side, rank, rg, hloc_x + (size_t)3*65536, hmir_x + (size_t)3*65536,
           Wdec_b, b_dec, out + (size_t)(T_ - 1)*B_*NO_, Scr);
}

extern "C" void kernel_launch(void* const* d_in, const int* in_sizes, int n_in,
                              void* d_out, int out_size, void* d_ws, size_t ws_size,
                              hipStream_t stream) {
  const float* x     = (const float*)d_in[0];
  const float* dt_p  = (const float*)d_in[1];
  const float* a_p   = (const float*)d_in[2];
  const float* W_enc = (const float*)d_in[3];
  const float* b_enc = (const float*)d_in[4];
  const float* W_rec = (const float*)d_in[5];
  const float* b_rec = (const float*)d_in[6];
  const float* W_dec = (const float*)d_in[7];
  const float* b_dec = (const float*)d_in[8];
  float* out = (float*)d_out;

  char* p = (char*)d_ws;
  bf16_t* hloc   = (bf16_t*)p;  p += (size_t)8*4*65536*2;   // 4MB
  bf16_t* hmir   = (bf16_t*)p;  p += (size_t)8*4*65536*2;   // 4MB
  bf16_t* pub    = (bf16_t*)p;  p += (size_t)8*2*65536*2;   // 2MB
  bf16_t* Wenc_b = (bf16_t*)p;  p += (size_t)NH_*NI_*2;     // 2MB
  bf16_t* Wdec_b = (bf16_t*)p;  p += (size_t)NO_*NH_*2;     // 1MB
  int*    sync_  = (int*)p;     p += 16384*4;               // 64KB (~13MB total)

  hipMemsetAsync(hloc, 0, (size_t)8*4*65536*2, stream);     // slot 3 = S_{-1} = 0
  hipMemsetAsync(hmir, 0, (size_t)8*4*65536*2, stream);
  hipMemsetAsync(sync_, 0, 16384*4, stream);

  k_cvt<<<128, 256, 0, stream>>>(W_enc, Wenc_b, NH_ * NI_);
  k_cvt<<<64, 256, 0, stream>>>(W_dec, Wdec_b, NO_ * NH_);

  k_prnn<<<dim3(256), dim3(1024), 0, stream>>>(
      x, dt_p, a_p, W_rec, Wenc_b, Wdec_b, b_rec, b_enc, b_dec,
      hloc, hmir, pub, sync_, out);
}